// Round 1
// baseline (102.925 us; speedup 1.0000x reference)
//
#include <hip/hip_runtime.h>
#include <math.h>
#include <stdint.h>

// Problem: bsz=16, sent_len=512 -> N=8192 rows, D=768, P=20, fp32 io.
// cos[n][p] = <rm, w2[p]> / (max(sqrt(<rr,w2[p]>),eps) * max(sqrt(<mm,w2[p]>),eps))
// Memory roofline: 50.3 MB in + 0.65 MB out ~ 8 us @ 6.3 TB/s. Pure-fp32 VALU
// cost ~5 us GPU-wide -> no MFMA needed; kill the per-block latency chain instead.

static constexpr int D_DIM   = 768;
static constexpr int NP      = 20;
static constexpr int NROWS   = 8192;
static constexpr int ROWS_PB = 16;                  // rows per block
static constexpr int NBLK    = NROWS / ROWS_PB;     // 512 blocks, 1/CU
static constexpr int NTHR    = 512;                 // 8 waves

// ---- LDS map (bytes) ----
// Sweep s in {0,1} = k-half [s*384, s*384+384). Within a sweep region:
//   [mat][row][kbyte]  (mat 0 = repres, 1 = max_att), linear as DMA'd.
static constexpr int HALF_B  = 1536;                // 384 floats per row per half
static constexpr int MAT_B   = ROWS_PB * HALF_B;    // 24576
static constexpr int SWEEP_B = 2 * MAT_B;           // 49152
static constexpr int W2_OFF  = 2 * SWEEP_B;         // 98304
static constexpr int LDS_B   = W2_OFF + NP * D_DIM * 4;  // 159744 <= 160K -> 1 blk/CU

// Reduction scratch (reuses A region after compute): [rnd][lrow][p][q][12]
static constexpr int SCR_K   = 12;                  // 8 partials + 4 pad (stride 12:
static constexpr int SCR_RND = 8 * NP * 3 * SCR_K;  //  granule stride 3, odd mod 8)

// Async global->LDS DMA, 16 B/lane (LDS dest = wave-uniform base + lane*16).
__device__ __forceinline__ void async_copy16(const void* g, void* l) {
  __builtin_amdgcn_global_load_lds(
      (const __attribute__((address_space(1))) unsigned int*)(uintptr_t)g,
      (__attribute__((address_space(3))) unsigned int*)(uint32_t)(uintptr_t)l,
      16, 0, 0);
}

__global__ __launch_bounds__(NTHR, 2) void atte_cos_v2(
    const float* __restrict__ repres,
    const float* __restrict__ max_att,
    const float* __restrict__ weight,
    float* __restrict__ out)
{
  extern __shared__ __align__(16) char smem[];
  const int tid  = threadIdx.x;
  const int wave = tid >> 6;
  const int lane = tid & 63;
  const int row0 = blockIdx.x * ROWS_PB;

  // ---- DMA one k-half of both matrices: 48 instrs/block, 6/wave, all in flight.
  // Per-lane GLOBAL address is a gather (handles the 1.5KB-row / 1KB-instr
  // straddle); LDS side is forced linear, which defines the LDS layout.
  auto dma_sweep = [&](int s) {
#pragma unroll
    for (int i = 0; i < 6; ++i) {
      const int ls  = wave * 6144 + i * 1024 + lane * 16;   // [0, 49152)
      const int mat = ls >= MAT_B;
      const int off = ls - (mat ? MAT_B : 0);               // [0, 24576)
      const int r   = off / HALF_B;                         // 0..15
      const int kb  = off - r * HALF_B;                     // row-half byte
      const char* src = (const char*)(mat ? max_att : repres)
                      + (size_t)(row0 + r) * 3072 + (size_t)s * HALF_B + kb;
      async_copy16(src, smem + s * SWEEP_B + ls);
    }
  };

  dma_sweep(0);

  // ---- w^2 -> LDS (f32, exact), coalesced float4; overlaps sweep-0 flight.
  {
    const float4* wsrc = (const float4*)weight;
    float4* wdst = (float4*)(smem + W2_OFF);
    for (int idx = tid; idx < NP * D_DIM / 4; idx += NTHR) {
      float4 w = wsrc[idx];
      w.x *= w.x; w.y *= w.y; w.z *= w.z; w.w *= w.w;
      wdst[idx] = w;
    }
  }

  dma_sweep(1);

  // thread -> (row, k-subset): row = tid>>5, k granules {ksub + 32j}.
  // A-read: 32 lanes hit 32 consecutive granules (conflict-free); the two rows
  // in a wave alias banks 2-way (free). w2-read: half-wave same-address
  // broadcast + consecutive granules (conflict-free). No padding needed.
  const int row  = tid >> 5;
  const int ksub = tid & 31;

  float accd[NP], acc1[NP], acc2[NP];
#pragma unroll
  for (int p = 0; p < NP; ++p) { accd[p] = 0.f; acc1[p] = 0.f; acc2[p] = 0.f; }

  auto compute_half = [&](const int s) {
    const char* ar = smem + s * SWEEP_B + row * HALF_B;
    const char* am = ar + MAT_B;
    const char* wb = smem + W2_OFF + s * HALF_B;   // w2[p] half-s, row stride 3072
#pragma unroll
    for (int j = 0; j < 3; ++j) {
      const int g16 = (ksub + 32 * j) * 16;
      const float4 r4 = *(const float4*)(ar + g16);
      const float4 m4 = *(const float4*)(am + g16);
      const float pd0 = r4.x * m4.x, pd1 = r4.y * m4.y, pd2 = r4.z * m4.z, pd3 = r4.w * m4.w;
      const float p10 = r4.x * r4.x, p11 = r4.y * r4.y, p12 = r4.z * r4.z, p13 = r4.w * r4.w;
      const float p20 = m4.x * m4.x, p21 = m4.y * m4.y, p22 = m4.z * m4.z, p23 = m4.w * m4.w;
#pragma unroll
      for (int p = 0; p < NP; ++p) {
        const float4 w4 = *(const float4*)(wb + p * 3072 + g16);
        accd[p] = fmaf(pd3, w4.w, fmaf(pd2, w4.z, fmaf(pd1, w4.y, fmaf(pd0, w4.x, accd[p]))));
        acc1[p] = fmaf(p13, w4.w, fmaf(p12, w4.z, fmaf(p11, w4.y, fmaf(p10, w4.x, acc1[p]))));
        acc2[p] = fmaf(p23, w4.w, fmaf(p22, w4.z, fmaf(p21, w4.y, fmaf(p20, w4.x, acc2[p]))));
      }
    }
  };

  // Phase 0: own sweep-0 DMAs + w^2 stores done (vmcnt(6): sweep-1's 6 may
  // stay in flight; lgkmcnt(0): w^2 ds_writes landed), then raw barrier for
  // cross-wave visibility. NOT __syncthreads() (it drains vmcnt(0) and would
  // serialize phase-1's loads behind phase-0 compute).
  __builtin_amdgcn_sched_barrier(0);
  __builtin_amdgcn_s_waitcnt(0x0076);   // vmcnt(6) lgkmcnt(0)
  __builtin_amdgcn_s_barrier();
  __builtin_amdgcn_sched_barrier(0);
  compute_half(0);

  // Phase 1: all DMAs done.
  __builtin_amdgcn_sched_barrier(0);
  __builtin_amdgcn_s_waitcnt(0x0F70);   // vmcnt(0)
  __builtin_amdgcn_s_barrier();
  __builtin_amdgcn_sched_barrier(0);
  compute_half(1);

  // ---- k reduction: 32 ksubs -> 8 partials in-wave (xor16, xor8 stay inside
  // each 32-lane row group), then one small LDS pass.
#pragma unroll
  for (int p = 0; p < NP; ++p) {
    accd[p] += __shfl_xor(accd[p], 16); acc1[p] += __shfl_xor(acc1[p], 16); acc2[p] += __shfl_xor(acc2[p], 16);
    accd[p] += __shfl_xor(accd[p],  8); acc1[p] += __shfl_xor(acc1[p],  8); acc2[p] += __shfl_xor(acc2[p],  8);
  }

  __builtin_amdgcn_sched_barrier(0);
  __builtin_amdgcn_s_waitcnt(0xC07F);   // lgkmcnt(0)
  __builtin_amdgcn_s_barrier();         // all A-region reads complete
  __builtin_amdgcn_sched_barrier(0);

  float* scr = (float*)smem;            // rounds use disjoint regions -> 1 barrier
  if (ksub < 8) {
    const int rnd = row >> 3, lrow = row & 7;
    float* base = scr + rnd * SCR_RND + (lrow * NP * 3) * SCR_K + ksub;
#pragma unroll
    for (int p = 0; p < NP; ++p) {
      base[(p * 3 + 0) * SCR_K] = accd[p];
      base[(p * 3 + 1) * SCR_K] = acc1[p];
      base[(p * 3 + 2) * SCR_K] = acc2[p];
    }
  }

  __builtin_amdgcn_sched_barrier(0);
  __builtin_amdgcn_s_waitcnt(0xC07F);   // scratch ds_writes landed
  __builtin_amdgcn_s_barrier();
  __builtin_amdgcn_sched_barrier(0);

  if (tid < 2 * 8 * NP) {               // 320 reducers, one (row,p) each
    const int rnd = tid / 160;
    const int t   = tid - rnd * 160;
    const int rr  = t / NP;
    const int p   = t - rr * NP;
    const float* b = scr + rnd * SCR_RND + ((rr * NP + p) * 3) * SCR_K;
    float s0 = 0.f, s1 = 0.f, s2 = 0.f;
#pragma unroll
    for (int c = 0; c < 8; ++c) {
      s0 += b[0 * SCR_K + c]; s1 += b[1 * SCR_K + c]; s2 += b[2 * SCR_K + c];
    }
    const float n1 = fmaxf(sqrtf(s1), 1e-8f);
    const float n2 = fmaxf(sqrtf(s2), 1e-8f);
    out[(size_t)(row0 + rnd * 8 + rr) * NP + p] = s0 / (n1 * n2);
  }
}

extern "C" void kernel_launch(void* const* d_in, const int* in_sizes, int n_in,
                              void* d_out, int out_size, void* d_ws, size_t ws_size,
                              hipStream_t stream) {
  static bool attr_set = false;
  if (!attr_set) {
    hipFuncSetAttribute(reinterpret_cast<const void*>(atte_cos_v2),
                        hipFuncAttributeMaxDynamicSharedMemorySize, LDS_B);
    attr_set = true;
  }
  atte_cos_v2<<<NBLK, NTHR, LDS_B, stream>>>(
      (const float*)d_in[0], (const float*)d_in[1],
      (const float*)d_in[2], (float*)d_out);
}

// Round 2
// 90.720 us; speedup vs baseline: 1.1345x; 1.1345x over previous
//
#include <hip/hip_runtime.h>
#include <math.h>
#include <stdint.h>

// Problem: bsz=16, sent_len=512 -> N=8192 rows, D=768, P=20, fp32 io.
// cos[n][p] = <rm,w2[p]> / (max(sqrt(<rr,w2[p]>),eps)*max(sqrt(<mm,w2[p]>),eps))
//
// v3: A (repres/max_att) has no cross-thread reuse in the MFMA formulation ->
// load fragments straight global->VGPR (16 rows x 128B-contiguous per wave-slice,
// fully coalesced at cache-line granularity). LDS holds ONLY the shared 31 KB
// bf16 w^2 tile (+ reduction scratch reused in place). One barrier before
// compute, no per-slice vmcnt gating. 31 KB LDS -> 4-5 blocks/CU: all 512
// blocks co-resident (ONE generation), 16-20 waves/CU hide load latency.

static constexpr int D_DIM   = 768;
static constexpr int NP      = 20;
static constexpr int NROWS   = 8192;
static constexpr int ROWS_PB = 16;                 // M-tile per block
static constexpr int BLOCKS  = NROWS / ROWS_PB;    // 512
static constexpr int NTHR    = 256;                // 4 waves
static constexpr int KW      = 192;                // split-K per wave
static constexpr int KSLICE  = 32;
static constexpr int NSLICES = KW / KSLICE;        // 6

typedef short  short8  __attribute__((ext_vector_type(8)));   // 8 bf16
typedef float  float4v __attribute__((ext_vector_type(4)));   // MFMA C/D

// B layout: [col][k] bf16, col stride 776*2 B (768 + 8 pad) -> 16-lane B-frag
// reads land 2 lanes/bank (free). Reduction scratch (24576 B) reuses this
// region after the last MFMA (barrier-separated).
static constexpr int B_CSTR = 776 * 2;
static constexpr int LDS_SZ = NP * B_CSTR;         // 31040 -> 5 blocks/CU by LDS

__device__ __forceinline__ unsigned short bf16_rne(float x) {
  unsigned u = __float_as_uint(x);
  u += 0x7FFFu + ((u >> 16) & 1u);
  return (unsigned short)(u >> 16);
}
__device__ __forceinline__ float bf16f(unsigned short h) {
  return __uint_as_float(((unsigned)h) << 16);
}

__global__ __launch_bounds__(NTHR) void atte_cos_v3(
    const float* __restrict__ repres,
    const float* __restrict__ max_att,
    const float* __restrict__ weight,
    float* __restrict__ out)
{
  const int tid  = threadIdx.x;
  const int wave = tid >> 6;
  const int lane = tid & 63;
  const int row0 = blockIdx.x * ROWS_PB;
  const int k0   = wave * KW;        // this wave's K range
  const int part = lane >> 4;        // k-offset part*8 within MFMA frags
  const int mrow = lane & 15;        // A row within tile

  __shared__ __align__(16) char smem[31104];

  // Per-lane global base for A fragments: row (row0+mrow), k = k0 + part*8.
  // One slice's wave footprint = 16 rows x 128 B contiguous each.
  const float* ar = repres  + (size_t)(row0 + mrow) * D_DIM + k0 + part * 8;
  const float* am = max_att + (size_t)(row0 + mrow) * D_DIM + k0 + part * 8;

  // Issue first two slices' A loads before B staging so everything overlaps.
  float4 fr[2][2], fm[2][2];         // [buf][half] - all indices compile-time
  fr[0][0] = *(const float4*)(ar + 0 * KSLICE);
  fr[0][1] = *(const float4*)(ar + 0 * KSLICE + 4);
  fm[0][0] = *(const float4*)(am + 0 * KSLICE);
  fm[0][1] = *(const float4*)(am + 0 * KSLICE + 4);
  fr[1][0] = *(const float4*)(ar + 1 * KSLICE);
  fr[1][1] = *(const float4*)(ar + 1 * KSLICE + 4);
  fm[1][0] = *(const float4*)(am + 1 * KSLICE);
  fm[1][1] = *(const float4*)(am + 1 * KSLICE + 4);

  // ---- B staging: w^2 -> bf16, [col][k] padded. 3840 float4s, 15/thread,
  // coalesced loads, 8 B ds_writes (2-bank stride -> conflict-free).
  {
    const float4* wsrc = (const float4*)weight;
#pragma unroll
    for (int it = 0; it < 15; ++it) {
      const int i   = it * NTHR + tid;       // 0..3839 = col*192 + kq
      const int col = i / 192;
      const int kq  = i - col * 192;
      float4 w = wsrc[i];
      ushort4 h;
      h.x = bf16_rne(w.x * w.x);
      h.y = bf16_rne(w.y * w.y);
      h.z = bf16_rne(w.z * w.z);
      h.w = bf16_rne(w.w * w.w);
      *(ushort4*)(smem + col * B_CSTR + kq * 8) = h;
    }
  }

  __syncthreads();   // B visible to all waves (also drains in-flight A, harmless)

  // B fragment pointers: B[k0+s*32+part*8 .. +7][col], 16 B contiguous in k.
  const char* b0p = smem + (lane & 15) * B_CSTR + (k0 + part * 8) * 2;
  const int   c1c = min(16 + (lane & 15), NP - 1);   // cols 20..31 junk, unstored
  const char* b1p = smem + c1c * B_CSTR + (k0 + part * 8) * 2;

  float4v acc[6] = {};   // [q*2 + ct]; q: 0=dot 1=||rw||^2 2=||mw||^2

#pragma unroll
  for (int s = 0; s < NSLICES; ++s) {
    float rv[8], mv[8];
    *(float4*)&rv[0] = fr[s & 1][0];
    *(float4*)&rv[4] = fr[s & 1][1];
    *(float4*)&mv[0] = fm[s & 1][0];
    *(float4*)&mv[4] = fm[s & 1][1];

    if (s + 2 < NSLICES) {   // depth-2 prefetch into the freed buffer
      fr[s & 1][0] = *(const float4*)(ar + (s + 2) * KSLICE);
      fr[s & 1][1] = *(const float4*)(ar + (s + 2) * KSLICE + 4);
      fm[s & 1][0] = *(const float4*)(am + (s + 2) * KSLICE);
      fm[s & 1][1] = *(const float4*)(am + (s + 2) * KSLICE + 4);
    }

    // Products fp32; dot gets hi+lo bf16 split (err 2^-17), norms hi-only.
    short8 a0h, a0l, a1h, a2h;
#pragma unroll
    for (int j = 0; j < 8; ++j) {
      const float pm = rv[j] * mv[j];
      const float pr = rv[j] * rv[j];
      const float pq = mv[j] * mv[j];
      const unsigned short h = bf16_rne(pm);
      a0h[j] = (short)h;
      a0l[j] = (short)bf16_rne(pm - bf16f(h));
      a1h[j] = (short)bf16_rne(pr);
      a2h[j] = (short)bf16_rne(pq);
    }

    const short8 b0 = *(const short8*)(b0p + s * 64);
    const short8 b1 = *(const short8*)(b1p + s * 64);

    acc[0] = __builtin_amdgcn_mfma_f32_16x16x32_bf16(a0h, b0, acc[0], 0, 0, 0);
    acc[0] = __builtin_amdgcn_mfma_f32_16x16x32_bf16(a0l, b0, acc[0], 0, 0, 0);
    acc[1] = __builtin_amdgcn_mfma_f32_16x16x32_bf16(a0h, b1, acc[1], 0, 0, 0);
    acc[1] = __builtin_amdgcn_mfma_f32_16x16x32_bf16(a0l, b1, acc[1], 0, 0, 0);
    acc[2] = __builtin_amdgcn_mfma_f32_16x16x32_bf16(a1h, b0, acc[2], 0, 0, 0);
    acc[3] = __builtin_amdgcn_mfma_f32_16x16x32_bf16(a1h, b1, acc[3], 0, 0, 0);
    acc[4] = __builtin_amdgcn_mfma_f32_16x16x32_bf16(a2h, b0, acc[4], 0, 0, 0);
    acc[5] = __builtin_amdgcn_mfma_f32_16x16x32_bf16(a2h, b1, acc[5], 0, 0, 0);
  }

  // ---- cross-wave K reduction: B region is dead, reuse as scratch (24576 B).
  __syncthreads();
#pragma unroll
  for (int qc = 0; qc < 6; ++qc)
    *(float4v*)(smem + ((qc * 4 + wave) * 64 + lane) * 16) = acc[qc];
  __syncthreads();

  if (wave < 2) {              // wave = column-tile; same (row,col)->lane map
    const int ct = wave;
    float4v c0 = {}, c1 = {}, c2 = {};
#pragma unroll
    for (int wv = 0; wv < 4; ++wv) {
      c0 += *(const float4v*)(smem + (((0 * 2 + ct) * 4 + wv) * 64 + lane) * 16);
      c1 += *(const float4v*)(smem + (((1 * 2 + ct) * 4 + wv) * 64 + lane) * 16);
      c2 += *(const float4v*)(smem + (((2 * 2 + ct) * 4 + wv) * 64 + lane) * 16);
    }
    const int col = ct * 16 + (lane & 15);
    if (col < NP) {
      const int rbase = row0 + (lane >> 4) * 4;   // C row = (lane>>4)*4 + reg
#pragma unroll
      for (int r = 0; r < 4; ++r) {
        const float n1 = fmaxf(sqrtf(c1[r]), 1e-8f);
        const float n2 = fmaxf(sqrtf(c2[r]), 1e-8f);
        out[(size_t)(rbase + r) * NP + col] = c0[r] / (n1 * n2);
      }
    }
  }
}

extern "C" void kernel_launch(void* const* d_in, const int* in_sizes, int n_in,
                              void* d_out, int out_size, void* d_ws, size_t ws_size,
                              hipStream_t stream) {
  atte_cos_v3<<<BLOCKS, NTHR, 0, stream>>>(
      (const float*)d_in[0], (const float*)d_in[1],
      (const float*)d_in[2], (float*)d_out);
}